// Round 4
// baseline (310.953 us; speedup 1.0000x reference)
//
#include <hip/hip_runtime.h>
#include <hip/hip_bf16.h>
#include <math.h>

// B=4, T=4096, C=1024, H=64 attention head, scores = K@Q^T, causal, softmax over s.
// R13: atomics -> private partial slabs + reduce kernel. attn 60->57us, total flat.
// R14 (this round): DISPATCH COUNT 4 -> 2. Evidence: visible GPU work (~85us) is
// far below dur_us (~180us); attn improvements don't move the total -> per-dispatch
// overhead hypothesis. (a) W f32->bf16 conversion folded into proj (each block
// converts into its own LDS staging; Wt_g and wtrans_kernel deleted). (b) reduction
// folded into attn via split-K last-block-done pattern (threadfence + per-tile
// atomic counter, zeroed by proj); single-chunk tiles (tt<8) normalize in-register.
// reduce_norm_kernel deleted. Attn math unchanged from R13.

typedef __attribute__((ext_vector_type(8))) short bf16x8;
typedef __attribute__((ext_vector_type(4))) short bf16x4;
typedef __attribute__((ext_vector_type(4))) float f32x4;

#define MFMA16(a, b, c) __builtin_amdgcn_mfma_f32_16x16x32_bf16(a, b, c, 0, 0, 0)

__device__ __forceinline__ short f2bf(float f) {
    union { float f; unsigned u; } v; v.f = f;
    unsigned r = v.u + 0x7FFFu + ((v.u >> 16) & 1u);   // RNE
    return (short)(r >> 16);
}

static constexpr int T = 4096;
static constexpr int C = 1024;
static constexpr int H = 64;
static constexpr int BATCH = 4;
static constexpr int M = BATCH * T;
static constexpr int CPB = 288;            // chunks per batch at CH=8 s-tiles/chunk
static constexpr float LOG2E = 1.44269504088896340736f;
static constexpr float KSCALE = 0.03125f * LOG2E;  // C^-0.5 * log2(e), folded into K

// ---------------------------------------------------------------------------
// Kernel 1: fused projection. Double-buffered LDS, one barrier per K-step.
// BM=64, BK=64, 512 threads. W converted f32->bf16 inline (768KB, L2-hot).
// K pre-scaled. V tile-transposed. Also zeroes the per-tile chunk counters.
// ---------------------------------------------------------------------------
__global__ __launch_bounds__(512) void proj_kernel(
    const float* __restrict__ x,
    const float* __restrict__ Wk, const float* __restrict__ Wq,
    const float* __restrict__ Wv,
    const float* __restrict__ bk, const float* __restrict__ bq,
    const float* __restrict__ bv,
    short* __restrict__ Kb, short* __restrict__ Qb, short* __restrict__ Vt,
    int* __restrict__ cnt)
{
    __shared__ short As[2][64][72];
    __shared__ short Ws[2][192][74];       // stride 74: spreads ds_write_b16 banks
    const int tid = threadIdx.x;
    const int wv = tid >> 6, lane = tid & 63, quad = lane >> 4, l16 = lane & 15;
    const int grp = wv >> 2, w4 = wv & 3;
    const int m0 = blockIdx.x * 64;
    const int arow = tid >> 3, ac8 = (tid & 7) * 8;
    const int kr = tid >> 3, h8 = (tid & 7) * 8;   // W staging map

    if (blockIdx.x == 0 && tid < BATCH * 64) cnt[tid] = 0;

    f32x4 acc[6];
    #pragma unroll
    for (int i = 0; i < 6; ++i)
        for (int j = 0; j < 4; ++j) acc[i][j] = 0.f;

    float4 xa0, xa1;
    float4 wk0, wk1, wq0, wq1, wv0, wv1;
    auto gload = [&](int k0) {
        xa0 = *(const float4*)&x[(size_t)(m0 + arow) * C + k0 + ac8];
        xa1 = *(const float4*)&x[(size_t)(m0 + arow) * C + k0 + ac8 + 4];
        const size_t wo = (size_t)(k0 + kr) * H + h8;
        wk0 = *(const float4*)&Wk[wo];  wk1 = *(const float4*)&Wk[wo + 4];
        wq0 = *(const float4*)&Wq[wo];  wq1 = *(const float4*)&Wq[wo + 4];
        wv0 = *(const float4*)&Wv[wo];  wv1 = *(const float4*)&Wv[wo + 4];
    };
    auto lwrite = [&](int p) {
        bf16x8 av;
        av[0] = f2bf(xa0.x); av[1] = f2bf(xa0.y); av[2] = f2bf(xa0.z); av[3] = f2bf(xa0.w);
        av[4] = f2bf(xa1.x); av[5] = f2bf(xa1.y); av[6] = f2bf(xa1.z); av[7] = f2bf(xa1.w);
        *(bf16x8*)&As[p][arow][ac8] = av;
        // transposed W staging: Ws[mat*64 + h][k]
        Ws[p][h8 + 0][kr] = f2bf(wk0.x);  Ws[p][h8 + 1][kr] = f2bf(wk0.y);
        Ws[p][h8 + 2][kr] = f2bf(wk0.z);  Ws[p][h8 + 3][kr] = f2bf(wk0.w);
        Ws[p][h8 + 4][kr] = f2bf(wk1.x);  Ws[p][h8 + 5][kr] = f2bf(wk1.y);
        Ws[p][h8 + 6][kr] = f2bf(wk1.z);  Ws[p][h8 + 7][kr] = f2bf(wk1.w);
        Ws[p][64 + h8 + 0][kr] = f2bf(wq0.x);  Ws[p][64 + h8 + 1][kr] = f2bf(wq0.y);
        Ws[p][64 + h8 + 2][kr] = f2bf(wq0.z);  Ws[p][64 + h8 + 3][kr] = f2bf(wq0.w);
        Ws[p][64 + h8 + 4][kr] = f2bf(wq1.x);  Ws[p][64 + h8 + 5][kr] = f2bf(wq1.y);
        Ws[p][64 + h8 + 6][kr] = f2bf(wq1.z);  Ws[p][64 + h8 + 7][kr] = f2bf(wq1.w);
        Ws[p][128 + h8 + 0][kr] = f2bf(wv0.x); Ws[p][128 + h8 + 1][kr] = f2bf(wv0.y);
        Ws[p][128 + h8 + 2][kr] = f2bf(wv0.z); Ws[p][128 + h8 + 3][kr] = f2bf(wv0.w);
        Ws[p][128 + h8 + 4][kr] = f2bf(wv1.x); Ws[p][128 + h8 + 5][kr] = f2bf(wv1.y);
        Ws[p][128 + h8 + 6][kr] = f2bf(wv1.z); Ws[p][128 + h8 + 7][kr] = f2bf(wv1.w);
    };

    gload(0);
    lwrite(0);
    __syncthreads();
    for (int it = 0; it < 16; ++it) {
        const int p = it & 1;
        if (it < 15) gload((it + 1) * 64);
        bf16x8 a0 = *(const bf16x8*)&As[p][w4 * 16 + l16][quad * 8];
        bf16x8 a1 = *(const bf16x8*)&As[p][w4 * 16 + l16][32 + quad * 8];
        #pragma unroll
        for (int tn = 0; tn < 6; ++tn) {
            bf16x8 b0 = *(const bf16x8*)&Ws[p][grp * 96 + tn * 16 + l16][quad * 8];
            bf16x8 b1 = *(const bf16x8*)&Ws[p][grp * 96 + tn * 16 + l16][32 + quad * 8];
            acc[tn] = MFMA16(a0, b0, acc[tn]);
            acc[tn] = MFMA16(a1, b1, acc[tn]);
        }
        if (it < 15) {
            lwrite((it + 1) & 1);
            __syncthreads();
        }
    }
    #pragma unroll
    for (int tn = 0; tn < 6; ++tn) {
        int gc = grp * 96 + tn * 16 + l16;
        int mat = gc >> 6, h = gc & 63;
        const float* bias = (mat == 0) ? bk : (mat == 1) ? bq : bv;
        float bb = bias[h];
        float sc = (mat == 0) ? KSCALE : 1.f;
        #pragma unroll
        for (int r = 0; r < 4; ++r) {
            int row = m0 + w4 * 16 + quad * 4 + r;
            short val = f2bf((acc[tn][r] + bb) * sc);
            if (mat == 0)      Kb[(size_t)row * H + h] = val;
            else if (mat == 1) Qb[(size_t)row * H + h] = val;
            else               Vt[((size_t)(row >> 6)) * 4096 + h * 64 + (row & 63)] = val;
        }
    }
}

// ---------------------------------------------------------------------------
// chunk mapping (CH=8): t-tile tt has k = tt/8+1 chunks; group k (tiles
// 8(k-1)..8k-1) starts at c = 4k(k-1) and holds 8k chunks. Chunks of a tile
// are CONTIGUOUS: base_c(tt) = 4k(k-1) + (tt-8(k-1))*k.
// ---------------------------------------------------------------------------
__device__ __forceinline__ void chunk_map8(int c, int& tt, int& chunk) {
    int k = 1;
    while (c >= 4 * k * (k + 1)) ++k;          // k in [1,8]
    int off = c - 4 * k * (k - 1);
    int q = off / k;
    tt = 8 * (k - 1) + q;
    chunk = off - q * k;
}

// ---------------------------------------------------------------------------
// Kernel 2: flash attention, self-reducing. 4 waves/block (256 thr); wave =
// (sh, sp): strip-pair sp owns t-strips {2sp,2sp+1}; s-half sh takes even/odd
// s-tiles. s-halves merged in LDS. k==1 tiles: normalize in-register, write
// out directly. k>1: store partial slab, threadfence + counter; last-arriving
// block reduces all k slabs + normalizes + writes out (split-K pattern).
// ---------------------------------------------------------------------------
__global__ __launch_bounds__(256) void attn_part_kernel(
    const short* __restrict__ Kb, const short* __restrict__ Qb,
    const short* __restrict__ Vt, float* __restrict__ Pb,
    float* __restrict__ lnPb, float* __restrict__ out,
    int* __restrict__ cnt)
{
    __shared__ short Pl[4][2][16][76];         // [wave][strip][t16][s]
    __shared__ float Ob[64][66];               // s-half merge buffer (padded)
    __shared__ float lnb[64];
    __shared__ float lnS[64];
    __shared__ int lastFlag;
    const int tid = threadIdx.x;
    const int wv = tid >> 6, lane = tid & 63;
    const int quad = lane >> 4, l16 = lane & 15;
    const int sp = wv & 1, sh = wv >> 1;       // strip-pair, s-half
    const int g = blockIdx.x;                  // 0..1151
    const int b = g & 3;                       // batch pinned per XCD
    const int c = CPB - 1 - (g >> 2);          // 0..287, heavy-first
    int tt, chunk;
    chunk_map8(c, tt, chunk);
    const int t0 = tt * 64;
    const int sA = sp * 2, sB = sp * 2 + 1;    // this wave's two strips
    const int st0 = chunk * 8;
    const int st1 = min(st0 + 8, tt + 1);
    const size_t base = (size_t)b * T * H;

    // K fragments (B operand, resident): B[k=h][n=t], lane l16 -> t-row
    const short* krA = Kb + base + (size_t)(t0 + sA * 16 + l16) * H;
    const short* krB = Kb + base + (size_t)(t0 + sB * 16 + l16) * H;
    bf16x8 kf0a = *(const bf16x8*)(krA + quad * 8);
    bf16x8 kf1a = *(const bf16x8*)(krA + 32 + quad * 8);
    bf16x8 kf0b = *(const bf16x8*)(krB + quad * 8);
    bf16x8 kf1b = *(const bf16x8*)(krB + 32 + quad * 8);

    bf16x8 ones;
    #pragma unroll
    for (int j = 0; j < 8; ++j) ones[j] = (short)0x3F80;   // bf16 1.0

    f32x4 oA[4], oB[4], lnA, lnB;
    #pragma unroll
    for (int i = 0; i < 4; ++i)
        for (int j = 0; j < 4; ++j) { oA[i][j] = 0.f; oB[i][j] = 0.f; }
    #pragma unroll
    for (int j = 0; j < 4; ++j) { lnA[j] = 0.f; lnB[j] = 0.f; }

    // this wave's s-tiles: st0+sh, st0+sh+2, ... (interleaved for balance)
    const int myb = st0 + sh;
    const short* qp = Qb + base + (size_t)(myb * 64 + l16) * H + quad * 8;
    const short* vp = Vt + ((size_t)(b * 64 + myb)) * 4096 + l16 * 64 + quad * 8;

    bf16x8 qc0[4], qc1[4];
    if (myb < st1) {
        #pragma unroll
        for (int tn = 0; tn < 4; ++tn) {
            qc0[tn] = *(const bf16x8*)(qp + tn * 1024);
            qc1[tn] = *(const bf16x8*)(qp + tn * 1024 + 32);
        }
    }

    for (int st = myb; st < st1; st += 2) {
        bf16x8 vb0[4], vb1[4];
        #pragma unroll
        for (int hn = 0; hn < 4; ++hn) {
            vb0[hn] = *(const bf16x8*)(vp + hn * 1024);
            vb1[hn] = *(const bf16x8*)(vp + hn * 1024 + 32);
        }
        // S^T for both strips: D[row=quad*4+r -> s][col=l16 -> t]
        f32x4 sAc[4], sBc[4];
        #pragma unroll
        for (int tn = 0; tn < 4; ++tn) {
            #pragma unroll
            for (int j = 0; j < 4; ++j) { sAc[tn][j] = 0.f; sBc[tn][j] = 0.f; }
            sAc[tn] = MFMA16(qc0[tn], kf0a, sAc[tn]);
            sAc[tn] = MFMA16(qc1[tn], kf1a, sAc[tn]);
            sBc[tn] = MFMA16(qc0[tn], kf0b, sBc[tn]);
            sBc[tn] = MFMA16(qc1[tn], kf1b, sBc[tn]);
        }
        // Q regs now dead -> load tile st+2's Q (covered by exp+LDS+PV below)
        const size_t qoff = (st + 2 < st1) ? 8192 : 0;
        #pragma unroll
        for (int tn = 0; tn < 4; ++tn) {
            qc0[tn] = *(const bf16x8*)(qp + qoff + tn * 1024);
            qc1[tn] = *(const bf16x8*)(qp + qoff + tn * 1024 + 32);
        }
        // p = exp2(s); mask only on the diagonal tile
        const bool diag = (st == tt);
        #pragma unroll
        for (int tn = 0; tn < 4; ++tn) {
            bf16x4 pa, pb;
            #pragma unroll
            for (int r = 0; r < 4; ++r) {
                float va = sAc[tn][r], vb = sBc[tn][r];
                if (diag) {
                    int scol = tn * 16 + quad * 4 + r;
                    if (scol > sA * 16 + l16) va = -INFINITY;
                    if (scol > sB * 16 + l16) vb = -INFINITY;
                }
                pa[r] = f2bf(exp2f(va));
                pb[r] = f2bf(exp2f(vb));
            }
            *(bf16x4*)&Pl[wv][0][l16][tn * 16 + quad * 4] = pa;
            *(bf16x4*)&Pl[wv][1][l16][tn * 16 + quad * 4] = pb;
        }
        // PV for both strips: A[m=t=l16][k=s] contiguous read-back
        bf16x8 aA0 = *(const bf16x8*)&Pl[wv][0][l16][quad * 8];
        bf16x8 aA1 = *(const bf16x8*)&Pl[wv][0][l16][32 + quad * 8];
        bf16x8 aB0 = *(const bf16x8*)&Pl[wv][1][l16][quad * 8];
        bf16x8 aB1 = *(const bf16x8*)&Pl[wv][1][l16][32 + quad * 8];
        #pragma unroll
        for (int hn = 0; hn < 4; ++hn) {
            oA[hn] = MFMA16(aA0, vb0[hn], oA[hn]);
            oA[hn] = MFMA16(aA1, vb1[hn], oA[hn]);
            oB[hn] = MFMA16(aB0, vb0[hn], oB[hn]);
            oB[hn] = MFMA16(aB1, vb1[hn], oB[hn]);
        }
        lnA = MFMA16(aA0, ones, lnA);
        lnA = MFMA16(aA1, ones, lnA);
        lnB = MFMA16(aB0, ones, lnB);
        lnB = MFMA16(aB1, ones, lnB);
        qp += 8192;
        vp += 8192;
    }

    // s-half merge: waves sh==1 stage partials in LDS; waves sh==0 add + emit.
    const int rbase = sp * 32;
    if (sh == 1) {
        #pragma unroll
        for (int hn = 0; hn < 4; ++hn)
            #pragma unroll
            for (int r = 0; r < 4; ++r) {
                Ob[rbase + quad * 4 + r][hn * 16 + l16] = oA[hn][r];
                Ob[rbase + 16 + quad * 4 + r][hn * 16 + l16] = oB[hn][r];
            }
        if (l16 == 0) {
            #pragma unroll
            for (int r = 0; r < 4; ++r) {
                lnb[rbase + quad * 4 + r] = lnA[r];
                lnb[rbase + 16 + quad * 4 + r] = lnB[r];
            }
        }
    }
    __syncthreads();

    const int k = tt / 8 + 1;                  // chunks for this tile
    if (k == 1) {
        // single-chunk tile: normalize in-register and write out directly
        if (sh == 0) {
            float invA[4], invB[4];
            #pragma unroll
            for (int r = 0; r < 4; ++r) {
                invA[r] = 1.f / (lnA[r] + lnb[rbase + quad * 4 + r]);
                invB[r] = 1.f / (lnB[r] + lnb[rbase + 16 + quad * 4 + r]);
            }
            #pragma unroll
            for (int hn = 0; hn < 4; ++hn)
                #pragma unroll
                for (int r = 0; r < 4; ++r) {
                    int ra = rbase + quad * 4 + r;
                    int rb = ra + 16;
                    float va = (oA[hn][r] + Ob[ra][hn * 16 + l16]) * invA[r];
                    float vb = (oB[hn][r] + Ob[rb][hn * 16 + l16]) * invB[r];
                    out[base + (size_t)(t0 + ra) * H + hn * 16 + l16] = va;
                    out[base + (size_t)(t0 + rb) * H + hn * 16 + l16] = vb;
                }
        }
        return;
    }

    // multi-chunk tile: emit partial slab
    if (sh == 0) {
        float* Pc = Pb + (size_t)(b * CPB + c) * 4096;   // this chunk's 64x64 slab
        #pragma unroll
        for (int hn = 0; hn < 4; ++hn)
            #pragma unroll
            for (int r = 0; r < 4; ++r) {
                int ra = rbase + quad * 4 + r;
                int rb = ra + 16;
                float va = oA[hn][r] + Ob[ra][hn * 16 + l16];
                float vb = oB[hn][r] + Ob[rb][hn * 16 + l16];
                Pc[(size_t)ra * 64 + hn * 16 + l16] = va;
                Pc[(size_t)rb * 64 + hn * 16 + l16] = vb;
            }
        if (l16 == 0) {
            float* lc = lnPb + (size_t)(b * CPB + c) * 64;
            #pragma unroll
            for (int r = 0; r < 4; ++r) {
                lc[rbase + quad * 4 + r] = lnA[r] + lnb[rbase + quad * 4 + r];
                lc[rbase + 16 + quad * 4 + r] = lnB[r] + lnb[rbase + 16 + quad * 4 + r];
            }
        }
    }
    __threadfence();                           // release: partials visible device-wide
    __syncthreads();
    if (tid == 0)
        lastFlag = (atomicAdd(&cnt[b * 64 + tt], 1) == k - 1);
    __syncthreads();
    if (!lastFlag) return;

    // last-arriving block: reduce all k slabs + normalize + write out
    __threadfence();                           // acquire
    const int base_c = 4 * k * (k - 1) + (tt - 8 * (k - 1)) * k;
    if (tid < 64) {
        float s = 0.f;
        for (int i = 0; i < k; ++i)
            s += lnPb[(size_t)(b * CPB + base_c + i) * 64 + tid];
        lnS[tid] = 1.f / s;
    }
    __syncthreads();
    float4 racc[4];
    #pragma unroll
    for (int j = 0; j < 4; ++j) racc[j] = {0.f, 0.f, 0.f, 0.f};
    for (int i = 0; i < k; ++i) {
        const float4* p4 = (const float4*)(Pb + (size_t)(b * CPB + base_c + i) * 4096);
        #pragma unroll
        for (int j = 0; j < 4; ++j) {
            float4 v = p4[tid + j * 256];
            racc[j].x += v.x; racc[j].y += v.y; racc[j].z += v.z; racc[j].w += v.w;
        }
    }
    float4* o4 = (float4*)out;
    const size_t obase = ((size_t)b * T + (size_t)tt * 64) * 16;   // float4 units
    #pragma unroll
    for (int j = 0; j < 4; ++j) {
        int idx = tid + j * 256;               // float4 index within 64x64 tile
        float inv = lnS[idx >> 4];             // 16 float4 per row
        float4 v = racc[j];
        v.x *= inv; v.y *= inv; v.z *= inv; v.w *= inv;
        o4[obase + idx] = v;
    }
}

// ---------------------------------------------------------------------------
extern "C" void kernel_launch(void* const* d_in, const int* in_sizes, int n_in,
                              void* d_out, int out_size, void* d_ws, size_t ws_size,
                              hipStream_t stream) {
    const float* x  = (const float*)d_in[0];
    const float* Wk = (const float*)d_in[1];
    const float* bk = (const float*)d_in[2];
    const float* Wq = (const float*)d_in[3];
    const float* bq = (const float*)d_in[4];
    const float* Wv = (const float*)d_in[5];
    const float* bv = (const float*)d_in[6];
    float* out = (float*)d_out;

    char* ws = (char*)d_ws;
    size_t off = 0;
    short* Kb   = (short*)(ws + off); off += (size_t)M * H * 2;            // 2 MB
    short* Qb   = (short*)(ws + off); off += (size_t)M * H * 2;            // 2 MB
    short* Vt   = (short*)(ws + off); off += (size_t)M * H * 2;            // 2 MB
    float* Pb   = (float*)(ws + off); off += (size_t)BATCH * CPB * 4096 * 4; // 18.9 MB
    float* lnPb = (float*)(ws + off); off += (size_t)BATCH * CPB * 64 * 4;   // 295 KB
    int*   cnt  = (int*)(ws + off);   off += (size_t)BATCH * 64 * 4;         // 1 KB
    // total ~25.2 MB

    proj_kernel<<<M / 64, 512, 0, stream>>>(x, Wk, Wq, Wv, bk, bq, bv,
                                            Kb, Qb, Vt, cnt);
    attn_part_kernel<<<BATCH * CPB, 256, 0, stream>>>(Kb, Qb, Vt, Pb, lnPb,
                                                      out, cnt);
}

// Round 5
// 181.150 us; speedup vs baseline: 1.7166x; 1.7166x over previous
//
#include <hip/hip_runtime.h>
#include <hip/hip_bf16.h>
#include <math.h>

// B=4, T=4096, C=1024, H=64 attention head, scores = K@Q^T, causal, softmax over s.
// R14 POST-MORTEM: split-K fusion with __threadfence() regressed attn 57->202us —
// device-scope release fences force per-block L2 writebacks across non-coherent
// XCD L2s; 1152 of them storm the TCCs. NEVER fence in the hot path on CDNA4.
// R15 (this round): revert attn/reduce to R13-exact (attn 57us verified, fence-free);
// keep R14's W-inline proj (wtrans dispatch + Wt_g round-trip deleted, no fence);
// add s_setprio(1) around attn MFMA clusters (T5: +4-7% on phase-diverse attn).
// 3 dispatches: proj -> attn -> reduce_norm.

typedef __attribute__((ext_vector_type(8))) short bf16x8;
typedef __attribute__((ext_vector_type(4))) short bf16x4;
typedef __attribute__((ext_vector_type(4))) float f32x4;

#define MFMA16(a, b, c) __builtin_amdgcn_mfma_f32_16x16x32_bf16(a, b, c, 0, 0, 0)

__device__ __forceinline__ short f2bf(float f) {
    union { float f; unsigned u; } v; v.f = f;
    unsigned r = v.u + 0x7FFFu + ((v.u >> 16) & 1u);   // RNE
    return (short)(r >> 16);
}

static constexpr int T = 4096;
static constexpr int C = 1024;
static constexpr int H = 64;
static constexpr int BATCH = 4;
static constexpr int M = BATCH * T;
static constexpr int CPB = 288;            // chunks per batch at CH=8 s-tiles/chunk
static constexpr float LOG2E = 1.44269504088896340736f;
static constexpr float KSCALE = 0.03125f * LOG2E;  // C^-0.5 * log2(e), folded into K

// ---------------------------------------------------------------------------
// Kernel 1: fused projection. Double-buffered LDS, one barrier per K-step.
// BM=64, BK=64, 512 threads. W converted f32->bf16 inline (768KB, L2-hot).
// K pre-scaled. V tile-transposed.
// ---------------------------------------------------------------------------
__global__ __launch_bounds__(512) void proj_kernel(
    const float* __restrict__ x,
    const float* __restrict__ Wk, const float* __restrict__ Wq,
    const float* __restrict__ Wv,
    const float* __restrict__ bk, const float* __restrict__ bq,
    const float* __restrict__ bv,
    short* __restrict__ Kb, short* __restrict__ Qb, short* __restrict__ Vt)
{
    __shared__ short As[2][64][72];
    __shared__ short Ws[2][192][74];       // stride 74: spreads ds_write_b16 banks
    const int tid = threadIdx.x;
    const int wv = tid >> 6, lane = tid & 63, quad = lane >> 4, l16 = lane & 15;
    const int grp = wv >> 2, w4 = wv & 3;
    const int m0 = blockIdx.x * 64;
    const int arow = tid >> 3, ac8 = (tid & 7) * 8;
    const int kr = tid >> 3, h8 = (tid & 7) * 8;   // W staging map

    f32x4 acc[6];
    #pragma unroll
    for (int i = 0; i < 6; ++i)
        for (int j = 0; j < 4; ++j) acc[i][j] = 0.f;

    float4 xa0, xa1;
    float4 wk0, wk1, wq0, wq1, wv0, wv1;
    auto gload = [&](int k0) {
        xa0 = *(const float4*)&x[(size_t)(m0 + arow) * C + k0 + ac8];
        xa1 = *(const float4*)&x[(size_t)(m0 + arow) * C + k0 + ac8 + 4];
        const size_t wo = (size_t)(k0 + kr) * H + h8;
        wk0 = *(const float4*)&Wk[wo];  wk1 = *(const float4*)&Wk[wo + 4];
        wq0 = *(const float4*)&Wq[wo];  wq1 = *(const float4*)&Wq[wo + 4];
        wv0 = *(const float4*)&Wv[wo];  wv1 = *(const float4*)&Wv[wo + 4];
    };
    auto lwrite = [&](int p) {
        bf16x8 av;
        av[0] = f2bf(xa0.x); av[1] = f2bf(xa0.y); av[2] = f2bf(xa0.z); av[3] = f2bf(xa0.w);
        av[4] = f2bf(xa1.x); av[5] = f2bf(xa1.y); av[6] = f2bf(xa1.z); av[7] = f2bf(xa1.w);
        *(bf16x8*)&As[p][arow][ac8] = av;
        // transposed W staging: Ws[mat*64 + h][k]
        Ws[p][h8 + 0][kr] = f2bf(wk0.x);  Ws[p][h8 + 1][kr] = f2bf(wk0.y);
        Ws[p][h8 + 2][kr] = f2bf(wk0.z);  Ws[p][h8 + 3][kr] = f2bf(wk0.w);
        Ws[p][h8 + 4][kr] = f2bf(wk1.x);  Ws[p][h8 + 5][kr] = f2bf(wk1.y);
        Ws[p][h8 + 6][kr] = f2bf(wk1.z);  Ws[p][h8 + 7][kr] = f2bf(wk1.w);
        Ws[p][64 + h8 + 0][kr] = f2bf(wq0.x);  Ws[p][64 + h8 + 1][kr] = f2bf(wq0.y);
        Ws[p][64 + h8 + 2][kr] = f2bf(wq0.z);  Ws[p][64 + h8 + 3][kr] = f2bf(wq0.w);
        Ws[p][64 + h8 + 4][kr] = f2bf(wq1.x);  Ws[p][64 + h8 + 5][kr] = f2bf(wq1.y);
        Ws[p][64 + h8 + 6][kr] = f2bf(wq1.z);  Ws[p][64 + h8 + 7][kr] = f2bf(wq1.w);
        Ws[p][128 + h8 + 0][kr] = f2bf(wv0.x); Ws[p][128 + h8 + 1][kr] = f2bf(wv0.y);
        Ws[p][128 + h8 + 2][kr] = f2bf(wv0.z); Ws[p][128 + h8 + 3][kr] = f2bf(wv0.w);
        Ws[p][128 + h8 + 4][kr] = f2bf(wv1.x); Ws[p][128 + h8 + 5][kr] = f2bf(wv1.y);
        Ws[p][128 + h8 + 6][kr] = f2bf(wv1.z); Ws[p][128 + h8 + 7][kr] = f2bf(wv1.w);
    };

    gload(0);
    lwrite(0);
    __syncthreads();
    for (int it = 0; it < 16; ++it) {
        const int p = it & 1;
        if (it < 15) gload((it + 1) * 64);
        bf16x8 a0 = *(const bf16x8*)&As[p][w4 * 16 + l16][quad * 8];
        bf16x8 a1 = *(const bf16x8*)&As[p][w4 * 16 + l16][32 + quad * 8];
        #pragma unroll
        for (int tn = 0; tn < 6; ++tn) {
            bf16x8 b0 = *(const bf16x8*)&Ws[p][grp * 96 + tn * 16 + l16][quad * 8];
            bf16x8 b1 = *(const bf16x8*)&Ws[p][grp * 96 + tn * 16 + l16][32 + quad * 8];
            acc[tn] = MFMA16(a0, b0, acc[tn]);
            acc[tn] = MFMA16(a1, b1, acc[tn]);
        }
        if (it < 15) {
            lwrite((it + 1) & 1);
            __syncthreads();
        }
    }
    #pragma unroll
    for (int tn = 0; tn < 6; ++tn) {
        int gc = grp * 96 + tn * 16 + l16;
        int mat = gc >> 6, h = gc & 63;
        const float* bias = (mat == 0) ? bk : (mat == 1) ? bq : bv;
        float bb = bias[h];
        float sc = (mat == 0) ? KSCALE : 1.f;
        #pragma unroll
        for (int r = 0; r < 4; ++r) {
            int row = m0 + w4 * 16 + quad * 4 + r;
            short val = f2bf((acc[tn][r] + bb) * sc);
            if (mat == 0)      Kb[(size_t)row * H + h] = val;
            else if (mat == 1) Qb[(size_t)row * H + h] = val;
            else               Vt[((size_t)(row >> 6)) * 4096 + h * 64 + (row & 63)] = val;
        }
    }
}

// ---------------------------------------------------------------------------
// chunk mapping (CH=8): t-tile tt has k = tt/8+1 chunks; group k (tiles
// 8(k-1)..8k-1) starts at c = 4k(k-1) and holds 8k chunks. Chunks of a tile
// are CONTIGUOUS: base_c(tt) = 4k(k-1) + (tt-8(k-1))*k.
// ---------------------------------------------------------------------------
__device__ __forceinline__ void chunk_map8(int c, int& tt, int& chunk) {
    int k = 1;
    while (c >= 4 * k * (k + 1)) ++k;          // k in [1,8]
    int off = c - 4 * k * (k - 1);
    int q = off / k;
    tt = 8 * (k - 1) + q;
    chunk = off - q * k;
}

// ---------------------------------------------------------------------------
// Kernel 2: flash attention partial (R13-exact + s_setprio around MFMA).
// 4 waves/block (256 thr); wave = (sh, sp): strip-pair sp owns t-strips
// {2sp,2sp+1}; s-half sh takes even/odd s-tiles. s-halves merged in LDS.
// NO ATOMICS, NO FENCES: each chunk stores its 64x64 O-partial + ln-partials
// to Pb/lnPb with plain coalesced stores.
// ---------------------------------------------------------------------------
__global__ __launch_bounds__(256) void attn_part_kernel(
    const short* __restrict__ Kb, const short* __restrict__ Qb,
    const short* __restrict__ Vt, float* __restrict__ Pb,
    float* __restrict__ lnPb)
{
    __shared__ short Pl[4][2][16][76];         // [wave][strip][t16][s]
    __shared__ float Ob[64][66];               // s-half merge buffer (padded)
    __shared__ float lnb[64];
    const int tid = threadIdx.x;
    const int wv = tid >> 6, lane = tid & 63;
    const int quad = lane >> 4, l16 = lane & 15;
    const int sp = wv & 1, sh = wv >> 1;       // strip-pair, s-half
    const int g = blockIdx.x;                  // 0..1151
    const int b = g & 3;                       // batch pinned per XCD
    const int c = CPB - 1 - (g >> 2);          // 0..287, heavy-first
    int tt, chunk;
    chunk_map8(c, tt, chunk);
    const int t0 = tt * 64;
    const int sA = sp * 2, sB = sp * 2 + 1;    // this wave's two strips
    const int st0 = chunk * 8;
    const int st1 = min(st0 + 8, tt + 1);
    const size_t base = (size_t)b * T * H;

    // K fragments (B operand, resident): B[k=h][n=t], lane l16 -> t-row
    const short* krA = Kb + base + (size_t)(t0 + sA * 16 + l16) * H;
    const short* krB = Kb + base + (size_t)(t0 + sB * 16 + l16) * H;
    bf16x8 kf0a = *(const bf16x8*)(krA + quad * 8);
    bf16x8 kf1a = *(const bf16x8*)(krA + 32 + quad * 8);
    bf16x8 kf0b = *(const bf16x8*)(krB + quad * 8);
    bf16x8 kf1b = *(const bf16x8*)(krB + 32 + quad * 8);

    bf16x8 ones;
    #pragma unroll
    for (int j = 0; j < 8; ++j) ones[j] = (short)0x3F80;   // bf16 1.0

    f32x4 oA[4], oB[4], lnA, lnB;
    #pragma unroll
    for (int i = 0; i < 4; ++i)
        for (int j = 0; j < 4; ++j) { oA[i][j] = 0.f; oB[i][j] = 0.f; }
    #pragma unroll
    for (int j = 0; j < 4; ++j) { lnA[j] = 0.f; lnB[j] = 0.f; }

    // this wave's s-tiles: st0+sh, st0+sh+2, ... (interleaved for balance)
    const int myb = st0 + sh;
    const short* qp = Qb + base + (size_t)(myb * 64 + l16) * H + quad * 8;
    const short* vp = Vt + ((size_t)(b * 64 + myb)) * 4096 + l16 * 64 + quad * 8;

    bf16x8 qc0[4], qc1[4];
    if (myb < st1) {
        #pragma unroll
        for (int tn = 0; tn < 4; ++tn) {
            qc0[tn] = *(const bf16x8*)(qp + tn * 1024);
            qc1[tn] = *(const bf16x8*)(qp + tn * 1024 + 32);
        }
    }

    for (int st = myb; st < st1; st += 2) {
        bf16x8 vb0[4], vb1[4];
        #pragma unroll
        for (int hn = 0; hn < 4; ++hn) {
            vb0[hn] = *(const bf16x8*)(vp + hn * 1024);
            vb1[hn] = *(const bf16x8*)(vp + hn * 1024 + 32);
        }
        // S^T for both strips: D[row=quad*4+r -> s][col=l16 -> t]
        f32x4 sAc[4], sBc[4];
        __builtin_amdgcn_s_setprio(1);
        #pragma unroll
        for (int tn = 0; tn < 4; ++tn) {
            #pragma unroll
            for (int j = 0; j < 4; ++j) { sAc[tn][j] = 0.f; sBc[tn][j] = 0.f; }
            sAc[tn] = MFMA16(qc0[tn], kf0a, sAc[tn]);
            sAc[tn] = MFMA16(qc1[tn], kf1a, sAc[tn]);
            sBc[tn] = MFMA16(qc0[tn], kf0b, sBc[tn]);
            sBc[tn] = MFMA16(qc1[tn], kf1b, sBc[tn]);
        }
        __builtin_amdgcn_s_setprio(0);
        // Q regs now dead -> load tile st+2's Q (covered by exp+LDS+PV below)
        const size_t qoff = (st + 2 < st1) ? 8192 : 0;
        #pragma unroll
        for (int tn = 0; tn < 4; ++tn) {
            qc0[tn] = *(const bf16x8*)(qp + qoff + tn * 1024);
            qc1[tn] = *(const bf16x8*)(qp + qoff + tn * 1024 + 32);
        }
        // p = exp2(s); mask only on the diagonal tile
        const bool diag = (st == tt);
        #pragma unroll
        for (int tn = 0; tn < 4; ++tn) {
            bf16x4 pa, pb;
            #pragma unroll
            for (int r = 0; r < 4; ++r) {
                float va = sAc[tn][r], vb = sBc[tn][r];
                if (diag) {
                    int scol = tn * 16 + quad * 4 + r;
                    if (scol > sA * 16 + l16) va = -INFINITY;
                    if (scol > sB * 16 + l16) vb = -INFINITY;
                }
                pa[r] = f2bf(exp2f(va));
                pb[r] = f2bf(exp2f(vb));
            }
            *(bf16x4*)&Pl[wv][0][l16][tn * 16 + quad * 4] = pa;
            *(bf16x4*)&Pl[wv][1][l16][tn * 16 + quad * 4] = pb;
        }
        // PV for both strips: A[m=t=l16][k=s] contiguous read-back
        bf16x8 aA0 = *(const bf16x8*)&Pl[wv][0][l16][quad * 8];
        bf16x8 aA1 = *(const bf16x8*)&Pl[wv][0][l16][32 + quad * 8];
        bf16x8 aB0 = *(const bf16x8*)&Pl[wv][1][l16][quad * 8];
        bf16x8 aB1 = *(const bf16x8*)&Pl[wv][1][l16][32 + quad * 8];
        __builtin_amdgcn_s_setprio(1);
        #pragma unroll
        for (int hn = 0; hn < 4; ++hn) {
            oA[hn] = MFMA16(aA0, vb0[hn], oA[hn]);
            oA[hn] = MFMA16(aA1, vb1[hn], oA[hn]);
            oB[hn] = MFMA16(aB0, vb0[hn], oB[hn]);
            oB[hn] = MFMA16(aB1, vb1[hn], oB[hn]);
        }
        lnA = MFMA16(aA0, ones, lnA);
        lnA = MFMA16(aA1, ones, lnA);
        lnB = MFMA16(aB0, ones, lnB);
        lnB = MFMA16(aB1, ones, lnB);
        __builtin_amdgcn_s_setprio(0);
        qp += 8192;
        vp += 8192;
    }

    // s-half merge: waves sh==1 stage partials in LDS; waves sh==0 add + store.
    const int rbase = sp * 32;
    if (sh == 1) {
        #pragma unroll
        for (int hn = 0; hn < 4; ++hn)
            #pragma unroll
            for (int r = 0; r < 4; ++r) {
                Ob[rbase + quad * 4 + r][hn * 16 + l16] = oA[hn][r];
                Ob[rbase + 16 + quad * 4 + r][hn * 16 + l16] = oB[hn][r];
            }
        if (l16 == 0) {
            #pragma unroll
            for (int r = 0; r < 4; ++r) {
                lnb[rbase + quad * 4 + r] = lnA[r];
                lnb[rbase + 16 + quad * 4 + r] = lnB[r];
            }
        }
    }
    __syncthreads();
    if (sh == 0) {
        float* Pc = Pb + (size_t)(b * CPB + c) * 4096;   // this chunk's 64x64 slab
        #pragma unroll
        for (int hn = 0; hn < 4; ++hn)
            #pragma unroll
            for (int r = 0; r < 4; ++r) {
                int ra = rbase + quad * 4 + r;
                int rb = ra + 16;
                float va = oA[hn][r] + Ob[ra][hn * 16 + l16];
                float vb = oB[hn][r] + Ob[rb][hn * 16 + l16];
                Pc[(size_t)ra * 64 + hn * 16 + l16] = va;
                Pc[(size_t)rb * 64 + hn * 16 + l16] = vb;
            }
        if (l16 == 0) {
            float* lc = lnPb + (size_t)(b * CPB + c) * 64;
            #pragma unroll
            for (int r = 0; r < 4; ++r) {
                lc[rbase + quad * 4 + r] = lnA[r] + lnb[rbase + quad * 4 + r];
                lc[rbase + 16 + quad * 4 + r] = lnB[r] + lnb[rbase + 16 + quad * 4 + r];
            }
        }
    }
}

// ---------------------------------------------------------------------------
// Kernel 3: reduce <=8 contiguous chunk partials per t-tile, normalize, write out.
// Grid: BATCH*64 blocks of 256 threads.
// ---------------------------------------------------------------------------
__global__ __launch_bounds__(256) void reduce_norm_kernel(
    const float* __restrict__ Pb, const float* __restrict__ lnPb,
    float* __restrict__ out)
{
    const int blk = blockIdx.x;                // b*64 + tt
    const int b = blk >> 6, tt = blk & 63;
    const int k = tt / 8 + 1;                  // number of chunk partials
    const int base_c = 4 * k * (k - 1) + (tt - 8 * (k - 1)) * k;
    const int tid = threadIdx.x;
    __shared__ float lnS[64];
    if (tid < 64) {
        float s = 0.f;
        for (int i = 0; i < k; ++i)
            s += lnPb[(size_t)(b * CPB + base_c + i) * 64 + tid];
        lnS[tid] = 1.f / s;
    }
    __syncthreads();
    float4 acc[4];
    #pragma unroll
    for (int j = 0; j < 4; ++j) acc[j] = {0.f, 0.f, 0.f, 0.f};
    for (int i = 0; i < k; ++i) {
        const float4* p4 = (const float4*)(Pb + (size_t)(b * CPB + base_c + i) * 4096);
        #pragma unroll
        for (int j = 0; j < 4; ++j) {
            float4 v = p4[tid + j * 256];
            acc[j].x += v.x; acc[j].y += v.y; acc[j].z += v.z; acc[j].w += v.w;
        }
    }
    float4* o4 = (float4*)out;
    const size_t obase = ((size_t)b * T + (size_t)tt * 64) * 16;   // float4 units
    #pragma unroll
    for (int j = 0; j < 4; ++j) {
        int idx = tid + j * 256;               // float4 index within 64x64 tile
        float inv = lnS[idx >> 4];             // 16 float4 per row
        float4 v = acc[j];
        v.x *= inv; v.y *= inv; v.z *= inv; v.w *= inv;
        o4[obase + idx] = v;
    }
}

// ---------------------------------------------------------------------------
extern "C" void kernel_launch(void* const* d_in, const int* in_sizes, int n_in,
                              void* d_out, int out_size, void* d_ws, size_t ws_size,
                              hipStream_t stream) {
    const float* x  = (const float*)d_in[0];
    const float* Wk = (const float*)d_in[1];
    const float* bk = (const float*)d_in[2];
    const float* Wq = (const float*)d_in[3];
    const float* bq = (const float*)d_in[4];
    const float* Wv = (const float*)d_in[5];
    const float* bv = (const float*)d_in[6];
    float* out = (float*)d_out;

    char* ws = (char*)d_ws;
    size_t off = 0;
    short* Kb   = (short*)(ws + off); off += (size_t)M * H * 2;            // 2 MB
    short* Qb   = (short*)(ws + off); off += (size_t)M * H * 2;            // 2 MB
    short* Vt   = (short*)(ws + off); off += (size_t)M * H * 2;            // 2 MB
    float* Pb   = (float*)(ws + off); off += (size_t)BATCH * CPB * 4096 * 4; // 18.9 MB
    float* lnPb = (float*)(ws + off); off += (size_t)BATCH * CPB * 64 * 4;   // 295 KB
    // total ~25.2 MB

    proj_kernel<<<M / 64, 512, 0, stream>>>(x, Wk, Wq, Wv, bk, bq, bv,
                                            Kb, Qb, Vt);
    attn_part_kernel<<<BATCH * CPB, 256, 0, stream>>>(Kb, Qb, Vt, Pb, lnPb);
    reduce_norm_kernel<<<BATCH * 64, 256, 0, stream>>>(Pb, lnPb, out);
}